// Round 5
// baseline (509.475 us; speedup 1.0000x reference)
//
#include <hip/hip_runtime.h>
#include <cstdint>
#include <cstddef>

// Problem constants (fixed by the reference)
#define NN 16384      // nodes
#define DIN 1024      // hid_size
#define DMID 1500     // hidden_size (logical)
#define DMIDP 1536    // padded to multiple of 256
#define NE 131072     // edges

typedef __bf16 bf16;
typedef __bf16 bf16x4 __attribute__((ext_vector_type(4)));
typedef __bf16 bf16x8 __attribute__((ext_vector_type(8)));
typedef float f32x4 __attribute__((ext_vector_type(4)));

#define GLOBAL_AS __attribute__((address_space(1)))
#define LDS_AS __attribute__((address_space(3)))

__device__ __forceinline__ void gload_lds16(const bf16* g, bf16* l) {
    // async 16B/lane global->LDS; LDS dest is wave-uniform base + lane*16
    __builtin_amdgcn_global_load_lds((GLOBAL_AS const unsigned int*)(g),
                                     (LDS_AS unsigned int*)(l), 16, 0, 0);
}

#define SBAR() asm volatile("s_barrier" ::: "memory")
#define WAITV_(N) asm volatile("s_waitcnt vmcnt(" #N ")" ::: "memory")
#define WAITV(N) WAITV_(N)
#define WAITL0() asm volatile("s_waitcnt lgkmcnt(0)" ::: "memory")

// ---------------- CSR build + normalization ----------------
__global__ void k_zero_cnt(int* cnt) {
    cnt[blockIdx.x * 256 + threadIdx.x] = 0;
}

__global__ void k_count(const int* __restrict__ dst, int* cnt) {
    int e = blockIdx.x * 256 + threadIdx.x;
    atomicAdd(&cnt[dst[e]], 1);
}

// single block, 1024 threads, 16 nodes each.
// rowptr = exclusive scan of PADDED counts (pad to multiple of 8); cursor = start; isd.
__global__ __launch_bounds__(1024) void k_scan(const int* __restrict__ cnt,
                                               int* __restrict__ rowptr,
                                               int* __restrict__ cursor,
                                               float* __restrict__ isd) {
    __shared__ int sums[1024];
    int t = threadIdx.x;
    int base = t * 16;
    int v[16], p[16];
    int s = 0;
#pragma unroll
    for (int k = 0; k < 16; ++k) {
        v[k] = cnt[base + k];
        p[k] = (v[k] + 7) & ~7;  // padded row length (multiple of 8)
        s += p[k];
    }
    sums[t] = s;
    __syncthreads();
    for (int off = 1; off < 1024; off <<= 1) {
        int y = (t >= off) ? sums[t - off] : 0;
        __syncthreads();
        sums[t] += y;
        __syncthreads();
    }
    int run = sums[t] - s;  // exclusive prefix
#pragma unroll
    for (int k = 0; k < 16; ++k) {
        rowptr[base + k] = run;
        cursor[base + k] = run;
        isd[base + k] = rsqrtf((float)(v[k] + 1));  // +1 self-loop
        run += p[k];
    }
    if (t == 1023) rowptr[NN] = run;
}

__global__ void k_fill(const int* __restrict__ src, const int* __restrict__ dst,
                       int* cursor, const float* __restrict__ isd,
                       int* __restrict__ csr_src, float* __restrict__ csr_w) {
    int e = blockIdx.x * 256 + threadIdx.x;
    int s = src[e], d = dst[e];
    int pos = atomicAdd(&cursor[d], 1);
    csr_src[pos] = s;
    csr_w[pos] = isd[s] * isd[d];
}

// fill pad slots: src = self (L1-hot row), w = 0 (contributes nothing)
__global__ void k_pad(const int* __restrict__ cnt, const int* __restrict__ rowptr,
                      int* __restrict__ csr_src, float* __restrict__ csr_w) {
    int i = blockIdx.x * 256 + threadIdx.x;
    int c = cnt[i];
    int p = (c + 7) & ~7;
    int base = rowptr[i];
    for (int q = c; q < p; ++q) {
        csr_src[base + q] = i;
        csr_w[base + q] = 0.0f;
    }
}

// ---------------- conversions ----------------
__global__ void k_cvt_x(const float4* __restrict__ x, bf16x4* __restrict__ xb) {
    int i = blockIdx.x * 256 + threadIdx.x;  // NN*DIN/4 total
    float4 v = x[i];
    bf16x4 o;
    o[0] = (bf16)v.x; o[1] = (bf16)v.y; o[2] = (bf16)v.z; o[3] = (bf16)v.w;
    xb[i] = o;
}

// W1 [1024][1500] f32 row-major -> W1b [1536][1024] bf16 (transposed, n-pad zero)
__global__ void k_cvt_w1(const float* __restrict__ W1, bf16* __restrict__ W1b) {
    int n = blockIdx.x;  // 0..1535
    for (int k = threadIdx.x; k < DIN; k += 256)
        W1b[n * DIN + k] = (n < DMID) ? (bf16)W1[(size_t)k * DMID + n] : (bf16)0.0f;
}

// W2 [1500][1024] f32 row-major -> W2b [1024][1536] bf16 (transposed, k-pad zero)
__global__ void k_cvt_w2(const float* __restrict__ W2, bf16* __restrict__ W2b) {
    int n = blockIdx.x;  // 0..1023
    for (int k = threadIdx.x; k < DMIDP; k += 256)
        W2b[n * DMIDP + k] = (k < DMID) ? (bf16)W2[(size_t)k * DIN + n] : (bf16)0.0f;
}

// ---------------- GEMM: C[M,N] = A[M,K] @ Bt[N,K]^T, bf16 in / bf16 out ----------------
// Parametric tile: BM x 256, BK=64, 8 waves (2M x 4N), per-wave (BM/2) x 64 output.
// R5 rationale: R1-R4 showed the intra-tile schedule is NOT the limiter at these
// shapes (4 structures all 666-680 TF). This round attacks two non-schedule defects:
//  (1) GEMM1 tail: 384 blocks @ 1/CU = 1.5 rounds (round 2 at 50% occupancy).
//      BM=128 -> grid 768 = 3 tailless rounds.
//  (2) Epilogue: 128 scalar column-strided bf16 stores/thread inflated WRITE_SIZE
//      49.2 vs 33.6 MB ideal (partial-line writebacks). LDS-transpose epilogue:
//      stage post-activation bf16 via a 32x264 LDS tile per mt-round, read back
//      row-contiguous, 2x16B stores per thread.
// Main loop: simplest of the tied variants (R3-style): per K-tile all reads+MFMA
// compiler-scheduled, single boundary {lgkm(0); vmcnt(0, cold: staged a full tile
// earlier); s_barrier; STAGE(t+2)}. T2 XOR swizzle kept (conflicts 0 since R1).
template <int BM, int K, int N, bool RELU_BIAS>
__global__ __launch_bounds__(512, 2) void gemm256(const bf16* __restrict__ A,
                                                  const bf16* __restrict__ Bt,
                                                  bf16* __restrict__ C,
                                                  const float* __restrict__ bias) {
    static_assert(BM == 128 || BM == 256, "");
    constexpr int NT = K / 64;
    constexpr int WM = BM / 2;       // per-wave rows
    constexpr int M_FR = WM / 16;    // 4 or 8
    constexpr int AR = BM / 64;      // A gloads/wave/tile (2 or 4)
    constexpr int TOK = AR + 4;      // gloads per wave per STAGE (6 or 8)
    __shared__ __align__(16) bf16 ldsA[2][BM * 64];
    __shared__ __align__(16) bf16 ldsB[2][256 * 64];
    const int tid = threadIdx.x;
    const int w = tid >> 6;
    const int lane = tid & 63;
    const int bm = blockIdx.x, bn = blockIdx.y;
    const int fr = lane & 15, fq = lane >> 4;
    const int wm = w >> 2;   // 0..1 : M half
    const int wn = w & 3;    // 0..3 : N quarter (64 cols)
    const int sx = fr & 7;   // read-side swizzle mask

    // staging: lane l covers row_local = l>>3 in each 8-row gload; fetch global
    // slot (l&7)^(l>>3) so the linear LDS write lands pre-swizzled (rule #21).
    const int lrow = lane >> 3;
    const int lslot = (lane & 7) ^ lrow;
    const bf16* gA = A + (size_t)(bm * BM + w * 8 * AR + lrow) * K + lslot * 8;
    const bf16* gB = Bt + (size_t)(bn * 256 + w * 32 + lrow) * K + lslot * 8;

    f32x4 acc[M_FR][4];
#pragma unroll
    for (int i = 0; i < M_FR; ++i)
#pragma unroll
        for (int j = 0; j < 4; ++j) acc[i][j] = {0.f, 0.f, 0.f, 0.f};

#define STAGE(T, BUF)                                                          \
    do {                                                                       \
        _Pragma("unroll") for (int r = 0; r < AR; ++r)                         \
            gload_lds16(gA + (size_t)(T) * 64 + (size_t)(r * 8) * K,           \
                        &ldsA[BUF][0] + w * (AR * 512) + r * 512);             \
        _Pragma("unroll") for (int r = 0; r < 4; ++r)                          \
            gload_lds16(gB + (size_t)(T) * 64 + (size_t)(r * 8) * K,           \
                        &ldsB[BUF][0] + w * 2048 + r * 512);                   \
    } while (0)

    // prologue: tiles 0,1 staged; wait tile 0 complete (tile 1 stays in flight)
    STAGE(0, 0);
    STAGE(1, 1);
    if constexpr (TOK == 6) { WAITV(6); } else { WAITV(8); }
    SBAR();

    for (int t = 0; t < NT; ++t) {
        const int c = t & 1;
#pragma unroll
        for (int ks = 0; ks < 2; ++ks) {
            bf16x8 bq[4];
#pragma unroll
            for (int nt = 0; nt < 4; ++nt) {
                int row = wn * 64 + nt * 16 + fr;
                int sl = ((ks << 2) | fq) ^ sx;
                bq[nt] = *(const bf16x8*)((const char*)&ldsB[c][0] +
                                          row * 128 + sl * 16);
            }
#pragma unroll
            for (int mh = 0; mh < M_FR / 4; ++mh) {
                bf16x8 af[4];
#pragma unroll
                for (int mt = 0; mt < 4; ++mt) {
                    int row = wm * WM + mh * 64 + mt * 16 + fr;
                    int sl = ((ks << 2) | fq) ^ sx;
                    af[mt] = *(const bf16x8*)((const char*)&ldsA[c][0] +
                                              row * 128 + sl * 16);
                }
                __builtin_amdgcn_s_setprio(1);
#pragma unroll
                for (int mt = 0; mt < 4; ++mt)
#pragma unroll
                    for (int nt = 0; nt < 4; ++nt)
                        acc[mh * 4 + mt][nt] =
                            __builtin_amdgcn_mfma_f32_16x16x32_bf16(
                                af[mt], bq[nt], acc[mh * 4 + mt][nt], 0, 0, 0);
                __builtin_amdgcn_s_setprio(0);
            }
        }
        // boundary: own reads of buf c drained (WAR), tile t+1's gloads landed
        // (RAW; cold — issued a full tile ago), barrier, restage c with t+2.
        if (t + 1 < NT) {
            WAITL0();
            WAITV(0);
            SBAR();
            if (t + 2 < NT) STAGE(t + 2, c);
        }
    }
#undef STAGE

    // ---- epilogue: LDS-transpose to coalesced 32B stores ----
    // acc layout (verified m89/m91): col = lane&15 (fr), row = fq*4 + r.
    // Per mt-round: all 8 waves stage 32 rows x 256 cols bf16 (post-activation)
    // into ldsE[32][264]; read back row-contiguous; 2x bf16x8 stores per thread.
    WAITL0();
    SBAR();  // all waves done with LDS main buffers
    float bv[4];
    if (RELU_BIAS) {
#pragma unroll
        for (int nt = 0; nt < 4; ++nt) {
            int col = bn * 256 + wn * 64 + nt * 16 + fr;
            bv[nt] = (col < DMID) ? bias[col] : 0.0f;
        }
    }
    constexpr int EP = 264;  // row stride (bf16): 528 B, 16B-aligned, de-conflicted
    bf16* ldsE = &ldsA[0][0];  // 32*264*2 = 16.5 KB <= 32 KB (BM=128 ldsA)
    const int erow = tid >> 4;       // 0..31
    const int ecseg = tid & 15;      // 16-col segment
#pragma unroll 1
    for (int mt = 0; mt < M_FR; ++mt) {
#pragma unroll
        for (int nt = 0; nt < 4; ++nt)
#pragma unroll
            for (int r = 0; r < 4; ++r) {
                float v = acc[mt][nt][r];
                if (RELU_BIAS) v = fmaxf(v + bv[nt], 0.0f);
                ldsE[(wm * 16 + fq * 4 + r) * EP + wn * 64 + nt * 16 + fr] =
                    (bf16)v;
            }
        __syncthreads();
        bf16x8 v0 = *(const bf16x8*)&ldsE[erow * EP + ecseg * 16];
        bf16x8 v1 = *(const bf16x8*)&ldsE[erow * EP + ecseg * 16 + 8];
        size_t grow = (size_t)bm * BM + (erow >> 4) * WM + mt * 16 + (erow & 15);
        *(bf16x8*)&C[grow * N + bn * 256 + ecseg * 16] = v0;
        *(bf16x8*)&C[grow * N + bn * 256 + ecseg * 16 + 8] = v1;
        __syncthreads();
    }
}

// ---------------- aggregation (CSR gather, barrier-free) ----------------
// XA[i] = isd_i^2 * X[i] + sum_j w_ij * X[j], 1024-wide bf16 in/out
__global__ __launch_bounds__(128) void k_aggX(const bf16* __restrict__ X,
                                              const int* __restrict__ rowptr,
                                              const int* __restrict__ csr_src,
                                              const float* __restrict__ csr_w,
                                              const float* __restrict__ isd,
                                              bf16* __restrict__ XA) {
    int i = blockIdx.x;
    int t = threadIdx.x;      // 128 threads * 8 cols = 1024
    int c0 = t * 8;
    int beg = rowptr[i], end = rowptr[i + 1];  // uniform; (end-beg) % 8 == 0
    float wi = isd[i];
    float w0 = wi * wi;
    float a[8];
    bf16x8 h = *(const bf16x8*)&X[(size_t)i * DIN + c0];
#pragma unroll
    for (int k = 0; k < 8; ++k) a[k] = w0 * (float)h[k];
    for (int e = beg; e < end; e += 8) {
        int j[8];
        float w[8];
        bf16x8 hv[8];
#pragma unroll
        for (int q = 0; q < 8; ++q) { j[q] = csr_src[e + q]; w[q] = csr_w[e + q]; }
#pragma unroll
        for (int q = 0; q < 8; ++q)
            hv[q] = *(const bf16x8*)&X[(size_t)j[q] * DIN + c0];
#pragma unroll
        for (int q = 0; q < 8; ++q)
#pragma unroll
            for (int k = 0; k < 8; ++k) a[k] += w[q] * (float)hv[q][k];
    }
    bf16x8 o;
#pragma unroll
    for (int k = 0; k < 8; ++k) o[k] = (bf16)a[k];
    *(bf16x8*)&XA[(size_t)i * DIN + c0] = o;
}

// layer 2: out[i] = isd_i^2 * H[i] + sum_j w_ij * H[j] + b2, f32 out
__global__ __launch_bounds__(128) void k_agg2(const bf16* __restrict__ H,
                                              const int* __restrict__ rowptr,
                                              const int* __restrict__ csr_src,
                                              const float* __restrict__ csr_w,
                                              const float* __restrict__ isd,
                                              const float* __restrict__ b2,
                                              float* __restrict__ out) {
    int i = blockIdx.x;
    int t = threadIdx.x;      // 128 threads * 8 cols = 1024
    int c0 = t * 8;
    int beg = rowptr[i], end = rowptr[i + 1];
    float wi = isd[i];
    float w0 = wi * wi;
    float a[8];
    bf16x8 h = *(const bf16x8*)&H[(size_t)i * DIN + c0];
#pragma unroll
    for (int k = 0; k < 8; ++k) a[k] = w0 * (float)h[k];
    for (int e = beg; e < end; e += 8) {
        int j[8];
        float w[8];
        bf16x8 hv[8];
#pragma unroll
        for (int q = 0; q < 8; ++q) { j[q] = csr_src[e + q]; w[q] = csr_w[e + q]; }
#pragma unroll
        for (int q = 0; q < 8; ++q)
            hv[q] = *(const bf16x8*)&H[(size_t)j[q] * DIN + c0];
#pragma unroll
        for (int q = 0; q < 8; ++q)
#pragma unroll
            for (int k = 0; k < 8; ++k) a[k] += w[q] * (float)hv[q][k];
    }
    float4 o0, o1;
    o0.x = a[0] + b2[c0 + 0]; o0.y = a[1] + b2[c0 + 1];
    o0.z = a[2] + b2[c0 + 2]; o0.w = a[3] + b2[c0 + 3];
    o1.x = a[4] + b2[c0 + 4]; o1.y = a[5] + b2[c0 + 5];
    o1.z = a[6] + b2[c0 + 6]; o1.w = a[7] + b2[c0 + 7];
    *(float4*)&out[(size_t)i * DIN + c0] = o0;
    *(float4*)&out[(size_t)i * DIN + c0 + 4] = o1;
}

extern "C" void kernel_launch(void* const* d_in, const int* in_sizes, int n_in,
                              void* d_out, int out_size, void* d_ws, size_t ws_size,
                              hipStream_t stream) {
    const float* x = (const float*)d_in[0];
    const int* ei = (const int*)d_in[1];
    const float* W1 = (const float*)d_in[2];
    const float* b1 = (const float*)d_in[3];
    const float* W2 = (const float*)d_in[4];
    const float* b2 = (const float*)d_in[5];
    float* out = (float*)d_out;
    const int* src = ei;
    const int* dst = ei + NE;

    // workspace layout (bytes), total ~122 MB
    char* ws = (char*)d_ws;
    int* cnt      = (int*)(ws + 0);          //  64 KB
    int* cursor   = (int*)(ws + 65536);      //  64 KB
    float* isd    = (float*)(ws + 131072);   //  64 KB
    int* rowptr   = (int*)(ws + 196608);     // 128 KB (NN+1 ints)
    int* csr_src  = (int*)(ws + 327680);     //   2 MB (padded <= 245760 entries)
    float* csr_w  = (float*)(ws + 2424832);  //   2 MB
    bf16* Xb      = (bf16*)(ws + 4521984);   // 33.55 MB (16384x1024)
    bf16* XA      = (bf16*)(ws + 38076416);  // 33.55 MB — reused as H2b
    bf16* W1b     = (bf16*)(ws + 71630848);  //  3.15 MB (1536x1024, transposed)
    bf16* W2b     = (bf16*)(ws + 74776576);  //  3.15 MB (1024x1536, transposed)
    bf16* Y1b     = (bf16*)(ws + 77922304);  // 50.33 MB (16384x1536)
    bf16* H2b     = XA;                      // XA dead after GEMM1

    // CSR + normalization
    k_zero_cnt<<<NN / 256, 256, 0, stream>>>(cnt);
    k_count<<<NE / 256, 256, 0, stream>>>(dst, cnt);
    k_scan<<<1, 1024, 0, stream>>>(cnt, rowptr, cursor, isd);
    k_fill<<<NE / 256, 256, 0, stream>>>(src, dst, cursor, isd, csr_src, csr_w);
    k_pad<<<NN / 256, 256, 0, stream>>>(cnt, rowptr, csr_src, csr_w);

    // bf16 conversions
    k_cvt_x<<<NN * DIN / 4 / 256, 256, 0, stream>>>((const float4*)x, (bf16x4*)Xb);
    k_cvt_w1<<<DMIDP, 256, 0, stream>>>(W1, W1b);
    k_cvt_w2<<<DIN, 256, 0, stream>>>(W2, W2b);

    // layer 1: XA = A_hat @ X ; Y1 = relu(XA @ W1 + b1)   [agg commutes with linear]
    k_aggX<<<NN, 128, 0, stream>>>(Xb, rowptr, csr_src, csr_w, isd, XA);
    dim3 g1(NN / 128, DMIDP / 256);   // 128x256 tile -> 768 blocks, 3 tailless rounds
    gemm256<128, DIN, DMIDP, true><<<g1, 512, 0, stream>>>(XA, W1b, Y1b, b1);

    // layer 2: H2 = Y1 @ W2 ; out = A_hat @ H2 + b2
    dim3 g2(NN / 256, DIN / 256);     // 256x256 tile -> 256 blocks, 1 round
    gemm256<256, DMIDP, DIN, false><<<g2, 512, 0, stream>>>(Y1b, W2b, H2b, nullptr);
    k_agg2<<<NN, 128, 0, stream>>>(H2b, rowptr, csr_src, csr_w, isd, b2, out);
}

// Round 6
// 399.759 us; speedup vs baseline: 1.2745x; 1.2745x over previous
//
#include <hip/hip_runtime.h>
#include <cstdint>
#include <cstddef>

// Problem constants (fixed by the reference)
#define NN 16384      // nodes
#define DIN 1024      // hid_size
#define DMID 1500     // hidden_size (logical)
#define DMIDP 1536    // padded to multiple of 256
#define NE 131072     // edges

typedef __bf16 bf16;
typedef __bf16 bf16x4 __attribute__((ext_vector_type(4)));
typedef __bf16 bf16x8 __attribute__((ext_vector_type(8)));
typedef float f32x4 __attribute__((ext_vector_type(4)));

#define GLOBAL_AS __attribute__((address_space(1)))
#define LDS_AS __attribute__((address_space(3)))

__device__ __forceinline__ void gload_lds16(const bf16* g, bf16* l) {
    // async 16B/lane global->LDS; LDS dest is wave-uniform base + lane*16
    __builtin_amdgcn_global_load_lds((GLOBAL_AS const unsigned int*)(g),
                                     (LDS_AS unsigned int*)(l), 16, 0, 0);
}

#define SBAR() asm volatile("s_barrier" ::: "memory")
#define WAITV_(N) asm volatile("s_waitcnt vmcnt(" #N ")" ::: "memory")
#define WAITV(N) WAITV_(N)
#define WAITL0() asm volatile("s_waitcnt lgkmcnt(0)" ::: "memory")

// ---------------- CSR build + normalization ----------------
__global__ void k_zero_cnt(int* cnt) {
    cnt[blockIdx.x * 256 + threadIdx.x] = 0;
}

__global__ void k_count(const int* __restrict__ dst, int* cnt) {
    int e = blockIdx.x * 256 + threadIdx.x;
    atomicAdd(&cnt[dst[e]], 1);
}

// single block, 1024 threads, 16 nodes each.
// rowptr = exclusive scan of PADDED counts (pad to multiple of 8); cursor = start; isd.
__global__ __launch_bounds__(1024) void k_scan(const int* __restrict__ cnt,
                                               int* __restrict__ rowptr,
                                               int* __restrict__ cursor,
                                               float* __restrict__ isd) {
    __shared__ int sums[1024];
    int t = threadIdx.x;
    int base = t * 16;
    int v[16], p[16];
    int s = 0;
#pragma unroll
    for (int k = 0; k < 16; ++k) {
        v[k] = cnt[base + k];
        p[k] = (v[k] + 7) & ~7;  // padded row length (multiple of 8)
        s += p[k];
    }
    sums[t] = s;
    __syncthreads();
    for (int off = 1; off < 1024; off <<= 1) {
        int y = (t >= off) ? sums[t - off] : 0;
        __syncthreads();
        sums[t] += y;
        __syncthreads();
    }
    int run = sums[t] - s;  // exclusive prefix
#pragma unroll
    for (int k = 0; k < 16; ++k) {
        rowptr[base + k] = run;
        cursor[base + k] = run;
        isd[base + k] = rsqrtf((float)(v[k] + 1));  // +1 self-loop
        run += p[k];
    }
    if (t == 1023) rowptr[NN] = run;
}

__global__ void k_fill(const int* __restrict__ src, const int* __restrict__ dst,
                       int* cursor, const float* __restrict__ isd,
                       int* __restrict__ csr_src, float* __restrict__ csr_w) {
    int e = blockIdx.x * 256 + threadIdx.x;
    int s = src[e], d = dst[e];
    int pos = atomicAdd(&cursor[d], 1);
    csr_src[pos] = s;
    csr_w[pos] = isd[s] * isd[d];
}

// fill pad slots: src = self (L1-hot row), w = 0 (contributes nothing)
__global__ void k_pad(const int* __restrict__ cnt, const int* __restrict__ rowptr,
                      int* __restrict__ csr_src, float* __restrict__ csr_w) {
    int i = blockIdx.x * 256 + threadIdx.x;
    int c = cnt[i];
    int p = (c + 7) & ~7;
    int base = rowptr[i];
    for (int q = c; q < p; ++q) {
        csr_src[base + q] = i;
        csr_w[base + q] = 0.0f;
    }
}

// ---------------- conversions ----------------
__global__ void k_cvt_x(const float4* __restrict__ x, bf16x4* __restrict__ xb) {
    int i = blockIdx.x * 256 + threadIdx.x;  // NN*DIN/4 total
    float4 v = x[i];
    bf16x4 o;
    o[0] = (bf16)v.x; o[1] = (bf16)v.y; o[2] = (bf16)v.z; o[3] = (bf16)v.w;
    xb[i] = o;
}

// W1 [1024][1500] f32 row-major -> W1b [1536][1024] bf16 (transposed, n-pad zero)
__global__ void k_cvt_w1(const float* __restrict__ W1, bf16* __restrict__ W1b) {
    int n = blockIdx.x;  // 0..1535
    for (int k = threadIdx.x; k < DIN; k += 256)
        W1b[n * DIN + k] = (n < DMID) ? (bf16)W1[(size_t)k * DMID + n] : (bf16)0.0f;
}

// W2 [1500][1024] f32 row-major -> W2b [1024][1536] bf16 (transposed, k-pad zero)
__global__ void k_cvt_w2(const float* __restrict__ W2, bf16* __restrict__ W2b) {
    int n = blockIdx.x;  // 0..1023
    for (int k = threadIdx.x; k < DMIDP; k += 256)
        W2b[n * DMIDP + k] = (k < DMID) ? (bf16)W2[(size_t)k * DIN + n] : (bf16)0.0f;
}

// ---------------- GEMM: C[M,N] = A[M,K] @ Bt[N,K]^T, bf16 in / bf16 out ----------------
// Parametric tile: BM x 256, BK=64, 8 waves (2M x 4N), per-wave (BM/2) x 64 output.
// R6: R5's LDS-transpose epilogue was the regression (16B-interleaved store
// footprint -> write-allocate + partial-line bursts: WRITE 49->293 MB). Reverted
// to the R4 SCALAR epilogue, whose WRITE was measured ~ideal (49.15 vs 50.33 MB).
// BM=128 for GEMM1 kept: grid 768 = 3 tailless rounds (vs 384 = 1.5 rounds with
// round 2 at 50% machine occupancy). GEMM2 stays BM=256 (256 blocks, 1 round).
// Main loop: R3-style single boundary sync per K-tile; T2 XOR swizzle (conflicts
// measured 0 since R1); T5 setprio around MFMA clusters.
template <int BM, int K, int N, bool RELU_BIAS>
__global__ __launch_bounds__(512, 2) void gemm256(const bf16* __restrict__ A,
                                                  const bf16* __restrict__ Bt,
                                                  bf16* __restrict__ C,
                                                  const float* __restrict__ bias) {
    static_assert(BM == 128 || BM == 256, "");
    constexpr int NT = K / 64;
    constexpr int WM = BM / 2;       // per-wave rows
    constexpr int M_FR = WM / 16;    // 4 or 8
    constexpr int AR = BM / 64;      // A gloads/wave/tile (2 or 4)
    constexpr int TOK = AR + 4;      // gloads per wave per STAGE (6 or 8)
    __shared__ __align__(16) bf16 ldsA[2][BM * 64];
    __shared__ __align__(16) bf16 ldsB[2][256 * 64];
    const int tid = threadIdx.x;
    const int w = tid >> 6;
    const int lane = tid & 63;
    const int bm = blockIdx.x, bn = blockIdx.y;
    const int fr = lane & 15, fq = lane >> 4;
    const int wm = w >> 2;   // 0..1 : M half
    const int wn = w & 3;    // 0..3 : N quarter (64 cols)
    const int sx = fr & 7;   // read-side swizzle mask

    // staging: lane l covers row_local = l>>3 in each 8-row gload; fetch global
    // slot (l&7)^(l>>3) so the linear LDS write lands pre-swizzled (rule #21).
    const int lrow = lane >> 3;
    const int lslot = (lane & 7) ^ lrow;
    const bf16* gA = A + (size_t)(bm * BM + w * 8 * AR + lrow) * K + lslot * 8;
    const bf16* gB = Bt + (size_t)(bn * 256 + w * 32 + lrow) * K + lslot * 8;

    f32x4 acc[M_FR][4];
#pragma unroll
    for (int i = 0; i < M_FR; ++i)
#pragma unroll
        for (int j = 0; j < 4; ++j) acc[i][j] = {0.f, 0.f, 0.f, 0.f};

#define STAGE(T, BUF)                                                          \
    do {                                                                       \
        _Pragma("unroll") for (int r = 0; r < AR; ++r)                         \
            gload_lds16(gA + (size_t)(T) * 64 + (size_t)(r * 8) * K,           \
                        &ldsA[BUF][0] + w * (AR * 512) + r * 512);             \
        _Pragma("unroll") for (int r = 0; r < 4; ++r)                          \
            gload_lds16(gB + (size_t)(T) * 64 + (size_t)(r * 8) * K,           \
                        &ldsB[BUF][0] + w * 2048 + r * 512);                   \
    } while (0)

    // prologue: tiles 0,1 staged; wait tile 0 complete (tile 1 stays in flight)
    STAGE(0, 0);
    STAGE(1, 1);
    if constexpr (TOK == 6) { WAITV(6); } else { WAITV(8); }
    SBAR();

    for (int t = 0; t < NT; ++t) {
        const int c = t & 1;
#pragma unroll
        for (int ks = 0; ks < 2; ++ks) {
            bf16x8 bq[4];
#pragma unroll
            for (int nt = 0; nt < 4; ++nt) {
                int row = wn * 64 + nt * 16 + fr;
                int sl = ((ks << 2) | fq) ^ sx;
                bq[nt] = *(const bf16x8*)((const char*)&ldsB[c][0] +
                                          row * 128 + sl * 16);
            }
#pragma unroll
            for (int mh = 0; mh < M_FR / 4; ++mh) {
                bf16x8 af[4];
#pragma unroll
                for (int mt = 0; mt < 4; ++mt) {
                    int row = wm * WM + mh * 64 + mt * 16 + fr;
                    int sl = ((ks << 2) | fq) ^ sx;
                    af[mt] = *(const bf16x8*)((const char*)&ldsA[c][0] +
                                              row * 128 + sl * 16);
                }
                __builtin_amdgcn_s_setprio(1);
#pragma unroll
                for (int mt = 0; mt < 4; ++mt)
#pragma unroll
                    for (int nt = 0; nt < 4; ++nt)
                        acc[mh * 4 + mt][nt] =
                            __builtin_amdgcn_mfma_f32_16x16x32_bf16(
                                af[mt], bq[nt], acc[mh * 4 + mt][nt], 0, 0, 0);
                __builtin_amdgcn_s_setprio(0);
            }
        }
        // boundary: own reads of buf c drained (WAR), tile t+1's gloads landed
        // (RAW; cold — issued a full tile ago), barrier, restage c with t+2.
        if (t + 1 < NT) {
            WAITL0();
            WAITV(0);
            SBAR();
            if (t + 2 < NT) STAGE(t + 2, c);
        }
    }
#undef STAGE

    // epilogue: R4 scalar store (C/D layout verified m89/m91: col = lane&15,
    // row = (lane>>4)*4 + reg). WRITE_SIZE measured ~ideal with this pattern.
    float bv[4];
    if (RELU_BIAS) {
#pragma unroll
        for (int nt = 0; nt < 4; ++nt) {
            int col = bn * 256 + wn * 64 + nt * 16 + fr;
            bv[nt] = (col < DMID) ? bias[col] : 0.0f;
        }
    }
#pragma unroll
    for (int mq = 0; mq < M_FR; ++mq) {
        int row0 = bm * BM + wm * WM + mq * 16 + fq * 4;
#pragma unroll
        for (int nt = 0; nt < 4; ++nt) {
            int col = bn * 256 + wn * 64 + nt * 16 + fr;
#pragma unroll
            for (int r = 0; r < 4; ++r) {
                float v = acc[mq][nt][r];
                if (RELU_BIAS) v = fmaxf(v + bv[nt], 0.0f);
                C[(size_t)(row0 + r) * N + col] = (bf16)v;
            }
        }
    }
}

// ---------------- aggregation (CSR gather, barrier-free) ----------------
// R6: edge loop restructured for MLP — 16 gathers in flight per thread when
// degree permits (16-batch main loop + one 8-batch tail; padding is mult-of-8
// so the tail is exactly 0 or 1 groups). If aggs are latency-bound this is the
// lever; if they're BW-floor'd it's a null (decision data for next round).

// XA[i] = isd_i^2 * X[i] + sum_j w_ij * X[j], 1024-wide bf16 in/out
__global__ __launch_bounds__(128) void k_aggX(const bf16* __restrict__ X,
                                              const int* __restrict__ rowptr,
                                              const int* __restrict__ csr_src,
                                              const float* __restrict__ csr_w,
                                              const float* __restrict__ isd,
                                              bf16* __restrict__ XA) {
    int i = blockIdx.x;
    int t = threadIdx.x;      // 128 threads * 8 cols = 1024
    int c0 = t * 8;
    int beg = rowptr[i], end = rowptr[i + 1];  // uniform; (end-beg) % 8 == 0
    float wi = isd[i];
    float w0 = wi * wi;
    float a[8];
    bf16x8 h = *(const bf16x8*)&X[(size_t)i * DIN + c0];
#pragma unroll
    for (int k = 0; k < 8; ++k) a[k] = w0 * (float)h[k];
    int e = beg;
    for (; e + 16 <= end; e += 16) {
        int j[16];
        float w[16];
        bf16x8 hv[16];
#pragma unroll
        for (int q = 0; q < 16; ++q) { j[q] = csr_src[e + q]; w[q] = csr_w[e + q]; }
#pragma unroll
        for (int q = 0; q < 16; ++q)
            hv[q] = *(const bf16x8*)&X[(size_t)j[q] * DIN + c0];
#pragma unroll
        for (int q = 0; q < 16; ++q)
#pragma unroll
            for (int k = 0; k < 8; ++k) a[k] += w[q] * (float)hv[q][k];
    }
    if (e < end) {  // exactly one 8-group remains
        int j[8];
        float w[8];
        bf16x8 hv[8];
#pragma unroll
        for (int q = 0; q < 8; ++q) { j[q] = csr_src[e + q]; w[q] = csr_w[e + q]; }
#pragma unroll
        for (int q = 0; q < 8; ++q)
            hv[q] = *(const bf16x8*)&X[(size_t)j[q] * DIN + c0];
#pragma unroll
        for (int q = 0; q < 8; ++q)
#pragma unroll
            for (int k = 0; k < 8; ++k) a[k] += w[q] * (float)hv[q][k];
    }
    bf16x8 o;
#pragma unroll
    for (int k = 0; k < 8; ++k) o[k] = (bf16)a[k];
    *(bf16x8*)&XA[(size_t)i * DIN + c0] = o;
}

// layer 2: out[i] = isd_i^2 * H[i] + sum_j w_ij * H[j] + b2, f32 out
__global__ __launch_bounds__(128) void k_agg2(const bf16* __restrict__ H,
                                              const int* __restrict__ rowptr,
                                              const int* __restrict__ csr_src,
                                              const float* __restrict__ csr_w,
                                              const float* __restrict__ isd,
                                              const float* __restrict__ b2,
                                              float* __restrict__ out) {
    int i = blockIdx.x;
    int t = threadIdx.x;      // 128 threads * 8 cols = 1024
    int c0 = t * 8;
    int beg = rowptr[i], end = rowptr[i + 1];
    float wi = isd[i];
    float w0 = wi * wi;
    float a[8];
    bf16x8 h = *(const bf16x8*)&H[(size_t)i * DIN + c0];
#pragma unroll
    for (int k = 0; k < 8; ++k) a[k] = w0 * (float)h[k];
    int e = beg;
    for (; e + 16 <= end; e += 16) {
        int j[16];
        float w[16];
        bf16x8 hv[16];
#pragma unroll
        for (int q = 0; q < 16; ++q) { j[q] = csr_src[e + q]; w[q] = csr_w[e + q]; }
#pragma unroll
        for (int q = 0; q < 16; ++q)
            hv[q] = *(const bf16x8*)&H[(size_t)j[q] * DIN + c0];
#pragma unroll
        for (int q = 0; q < 16; ++q)
#pragma unroll
            for (int k = 0; k < 8; ++k) a[k] += w[q] * (float)hv[q][k];
    }
    if (e < end) {  // exactly one 8-group remains
        int j[8];
        float w[8];
        bf16x8 hv[8];
#pragma unroll
        for (int q = 0; q < 8; ++q) { j[q] = csr_src[e + q]; w[q] = csr_w[e + q]; }
#pragma unroll
        for (int q = 0; q < 8; ++q)
            hv[q] = *(const bf16x8*)&H[(size_t)j[q] * DIN + c0];
#pragma unroll
        for (int q = 0; q < 8; ++q)
#pragma unroll
            for (int k = 0; k < 8; ++k) a[k] += w[q] * (float)hv[q][k];
    }
    float4 o0, o1;
    o0.x = a[0] + b2[c0 + 0]; o0.y = a[1] + b2[c0 + 1];
    o0.z = a[2] + b2[c0 + 2]; o0.w = a[3] + b2[c0 + 3];
    o1.x = a[4] + b2[c0 + 4]; o1.y = a[5] + b2[c0 + 5];
    o1.z = a[6] + b2[c0 + 6]; o1.w = a[7] + b2[c0 + 7];
    *(float4*)&out[(size_t)i * DIN + c0] = o0;
    *(float4*)&out[(size_t)i * DIN + c0 + 4] = o1;
}

extern "C" void kernel_launch(void* const* d_in, const int* in_sizes, int n_in,
                              void* d_out, int out_size, void* d_ws, size_t ws_size,
                              hipStream_t stream) {
    const float* x = (const float*)d_in[0];
    const int* ei = (const int*)d_in[1];
    const float* W1 = (const float*)d_in[2];
    const float* b1 = (const float*)d_in[3];
    const float* W2 = (const float*)d_in[4];
    const float* b2 = (const float*)d_in[5];
    float* out = (float*)d_out;
    const int* src = ei;
    const int* dst = ei + NE;

    // workspace layout (bytes), total ~122 MB
    char* ws = (char*)d_ws;
    int* cnt      = (int*)(ws + 0);          //  64 KB
    int* cursor   = (int*)(ws + 65536);      //  64 KB
    float* isd    = (float*)(ws + 131072);   //  64 KB
    int* rowptr   = (int*)(ws + 196608);     // 128 KB (NN+1 ints)
    int* csr_src  = (int*)(ws + 327680);     //   2 MB (padded <= 245760 entries)
    float* csr_w  = (float*)(ws + 2424832);  //   2 MB
    bf16* Xb      = (bf16*)(ws + 4521984);   // 33.55 MB (16384x1024)
    bf16* XA      = (bf16*)(ws + 38076416);  // 33.55 MB — reused as H2b
    bf16* W1b     = (bf16*)(ws + 71630848);  //  3.15 MB (1536x1024, transposed)
    bf16* W2b     = (bf16*)(ws + 74776576);  //  3.15 MB (1024x1536, transposed)
    bf16* Y1b     = (bf16*)(ws + 77922304);  // 50.33 MB (16384x1536)
    bf16* H2b     = XA;                      // XA dead after GEMM1

    // CSR + normalization
    k_zero_cnt<<<NN / 256, 256, 0, stream>>>(cnt);
    k_count<<<NE / 256, 256, 0, stream>>>(dst, cnt);
    k_scan<<<1, 1024, 0, stream>>>(cnt, rowptr, cursor, isd);
    k_fill<<<NE / 256, 256, 0, stream>>>(src, dst, cursor, isd, csr_src, csr_w);
    k_pad<<<NN / 256, 256, 0, stream>>>(cnt, rowptr, csr_src, csr_w);

    // bf16 conversions
    k_cvt_x<<<NN * DIN / 4 / 256, 256, 0, stream>>>((const float4*)x, (bf16x4*)Xb);
    k_cvt_w1<<<DMIDP, 256, 0, stream>>>(W1, W1b);
    k_cvt_w2<<<DIN, 256, 0, stream>>>(W2, W2b);

    // layer 1: XA = A_hat @ X ; Y1 = relu(XA @ W1 + b1)   [agg commutes with linear]
    k_aggX<<<NN, 128, 0, stream>>>(Xb, rowptr, csr_src, csr_w, isd, XA);
    dim3 g1(NN / 128, DMIDP / 256);   // 128x256 tile -> 768 blocks, 3 tailless rounds
    gemm256<128, DIN, DMIDP, true><<<g1, 512, 0, stream>>>(XA, W1b, Y1b, b1);

    // layer 2: H2 = Y1 @ W2 ; out = A_hat @ H2 + b2
    dim3 g2(NN / 256, DIN / 256);     // 256x256 tile -> 256 blocks, 1 round
    gemm256<256, DMIDP, DIN, false><<<g2, 512, 0, stream>>>(Y1b, W2b, H2b, nullptr);
    k_agg2<<<NN, 128, 0, stream>>>(H2b, rowptr, csr_src, csr_w, isd, b2, out);
}

// Round 7
// 370.837 us; speedup vs baseline: 1.3739x; 1.0780x over previous
//
#include <hip/hip_runtime.h>
#include <cstdint>
#include <cstddef>

// Problem constants (fixed by the reference)
#define NN 16384      // nodes
#define DIN 1024      // hid_size
#define DMID 1500     // hidden_size (logical)
#define DMIDP 1536    // padded to multiple of 128
#define NE 131072     // edges

typedef __bf16 bf16;
typedef __bf16 bf16x4 __attribute__((ext_vector_type(4)));
typedef __bf16 bf16x8 __attribute__((ext_vector_type(8)));
typedef float f32x4 __attribute__((ext_vector_type(4)));

#define GLOBAL_AS __attribute__((address_space(1)))
#define LDS_AS __attribute__((address_space(3)))

__device__ __forceinline__ void gload_lds16(const bf16* g, bf16* l) {
    // async 16B/lane global->LDS; LDS dest is wave-uniform base + lane*16
    __builtin_amdgcn_global_load_lds((GLOBAL_AS const unsigned int*)(g),
                                     (LDS_AS unsigned int*)(l), 16, 0, 0);
}

#define SBAR() asm volatile("s_barrier" ::: "memory")
#define WAITV_(N) asm volatile("s_waitcnt vmcnt(" #N ")" ::: "memory")
#define WAITV(N) WAITV_(N)
#define WAITL0() asm volatile("s_waitcnt lgkmcnt(0)" ::: "memory")

// ---------------- CSR build + normalization ----------------
__global__ void k_zero_cnt(int* cnt) {
    cnt[blockIdx.x * 256 + threadIdx.x] = 0;
}

__global__ void k_count(const int* __restrict__ dst, int* cnt) {
    int e = blockIdx.x * 256 + threadIdx.x;
    atomicAdd(&cnt[dst[e]], 1);
}

// single block, 1024 threads, 16 nodes each.
// rowptr = exclusive scan of PADDED counts (pad to multiple of 8); cursor = start; isd.
__global__ __launch_bounds__(1024) void k_scan(const int* __restrict__ cnt,
                                               int* __restrict__ rowptr,
                                               int* __restrict__ cursor,
                                               float* __restrict__ isd) {
    __shared__ int sums[1024];
    int t = threadIdx.x;
    int base = t * 16;
    int v[16], p[16];
    int s = 0;
#pragma unroll
    for (int k = 0; k < 16; ++k) {
        v[k] = cnt[base + k];
        p[k] = (v[k] + 7) & ~7;  // padded row length (multiple of 8)
        s += p[k];
    }
    sums[t] = s;
    __syncthreads();
    for (int off = 1; off < 1024; off <<= 1) {
        int y = (t >= off) ? sums[t - off] : 0;
        __syncthreads();
        sums[t] += y;
        __syncthreads();
    }
    int run = sums[t] - s;  // exclusive prefix
#pragma unroll
    for (int k = 0; k < 16; ++k) {
        rowptr[base + k] = run;
        cursor[base + k] = run;
        isd[base + k] = rsqrtf((float)(v[k] + 1));  // +1 self-loop
        run += p[k];
    }
    if (t == 1023) rowptr[NN] = run;
}

__global__ void k_fill(const int* __restrict__ src, const int* __restrict__ dst,
                       int* cursor, const float* __restrict__ isd,
                       int* __restrict__ csr_src, float* __restrict__ csr_w) {
    int e = blockIdx.x * 256 + threadIdx.x;
    int s = src[e], d = dst[e];
    int pos = atomicAdd(&cursor[d], 1);
    csr_src[pos] = s;
    csr_w[pos] = isd[s] * isd[d];
}

// fill pad slots: src = self (L1-hot row), w = 0 (contributes nothing)
__global__ void k_pad(const int* __restrict__ cnt, const int* __restrict__ rowptr,
                      int* __restrict__ csr_src, float* __restrict__ csr_w) {
    int i = blockIdx.x * 256 + threadIdx.x;
    int c = cnt[i];
    int p = (c + 7) & ~7;
    int base = rowptr[i];
    for (int q = c; q < p; ++q) {
        csr_src[base + q] = i;
        csr_w[base + q] = 0.0f;
    }
}

// ---------------- conversions ----------------
__global__ void k_cvt_x(const float4* __restrict__ x, bf16x4* __restrict__ xb) {
    int i = blockIdx.x * 256 + threadIdx.x;  // NN*DIN/4 total
    float4 v = x[i];
    bf16x4 o;
    o[0] = (bf16)v.x; o[1] = (bf16)v.y; o[2] = (bf16)v.z; o[3] = (bf16)v.w;
    xb[i] = o;
}

// R7: LDS-tile transposes for the weight conversions. The old per-column
// kernels did ~1.5M strided scalar f32 reads each (64B line inflation).
// Now: 32x32 f32 tile staged in LDS (both global sides coalesced).

// W1 [1024][1500] f32 -> W1b [1536][1024] bf16 (W1b[n][k] = W1[k][n], n-pad 0)
// grid (DMIDP/32 = 48, DIN/32 = 32), 256 threads
__global__ __launch_bounds__(256) void k_cvt_w1(const float* __restrict__ W1,
                                                bf16* __restrict__ W1b) {
    __shared__ float t[32][33];
    int n0 = blockIdx.x * 32;   // 0..1535 (output row = W1 col)
    int k0 = blockIdx.y * 32;   // 0..1023
    int tx = threadIdx.x & 31, ty = threadIdx.x >> 5;  // ty 0..7
#pragma unroll
    for (int p = 0; p < 4; ++p) {
        int n = n0 + tx;
        t[p * 8 + ty][tx] = (n < DMID)
            ? W1[(size_t)(k0 + p * 8 + ty) * DMID + n] : 0.0f;
    }
    __syncthreads();
#pragma unroll
    for (int p = 0; p < 4; ++p) {
        int n = n0 + p * 8 + ty;
        W1b[(size_t)n * DIN + k0 + tx] = (bf16)t[tx][p * 8 + ty];
    }
}

// W2 [1500][1024] f32 -> W2b [1024][1536] bf16 (W2b[n][k] = W2[k][n], k-pad 0)
// grid (DIN/32 = 32, DMIDP/32 = 48), 256 threads
__global__ __launch_bounds__(256) void k_cvt_w2(const float* __restrict__ W2,
                                                bf16* __restrict__ W2b) {
    __shared__ float t[32][33];
    int n0 = blockIdx.x * 32;   // 0..1023 (output row = W2 col)
    int k0 = blockIdx.y * 32;   // 0..1535
    int tx = threadIdx.x & 31, ty = threadIdx.x >> 5;
#pragma unroll
    for (int p = 0; p < 4; ++p) {
        int k = k0 + p * 8 + ty;
        t[p * 8 + ty][tx] = (k < DMID)
            ? W2[(size_t)k * DIN + n0 + tx] : 0.0f;
    }
    __syncthreads();
#pragma unroll
    for (int p = 0; p < 4; ++p) {
        int n = n0 + p * 8 + ty;
        W2b[(size_t)n * DMIDP + k0 + tx] = (bf16)t[tx][p * 8 + ty];
    }
}

// ---------------- GEMM: C[M,N] = A[M,K] @ Bt[N,K]^T, bf16 in / bf16 out ----------------
// R7: 128x128 tile, BK=64, DOUBLE-BUFFERED at 64 KB LDS -> 2 blocks/CU.
// R1-R6 post-mortem: all 256^2 variants ran 1 block/CU (96-128 KB LDS,
// Occupancy ~20%) — every barrier drain was pure CU idle, which is why four
// different intra-block schedules were indistinguishable (666-680 TF). m97's
// 874 TF came from 3 blocks/CU implicit cross-block overlap (m114), not from
// its schedule. This config restores >=2 blocks/CU while keeping T2 swizzle
// (0 conflicts since R1), width-16 gload_lds, setprio, and the R3-style
// single-boundary sync. 4 waves (2Mx2N), per-wave 64x64 output.
// Grids: GEMM1 (128,12)=1536 = 3 tailless co-residency rounds @2/CU;
//        GEMM2 (128,8)=1024 = 2 rounds.
template <int K, int N, bool RELU_BIAS>
__global__ __launch_bounds__(256, 2) void gemm128(const bf16* __restrict__ A,
                                                  const bf16* __restrict__ Bt,
                                                  bf16* __restrict__ C,
                                                  const float* __restrict__ bias) {
    constexpr int NT = K / 64;
    __shared__ __align__(16) bf16 ldsA[2][128 * 64];  // 2 x 16 KB
    __shared__ __align__(16) bf16 ldsB[2][128 * 64];  // 2 x 16 KB  -> 64 KB total
    const int tid = threadIdx.x;
    const int w = tid >> 6;          // 0..3
    const int lane = tid & 63;
    const int bm = blockIdx.x, bn = blockIdx.y;
    const int fr = lane & 15, fq = lane >> 4;
    const int wm = w & 1;            // M half (64 rows)
    const int wn = w >> 1;           // N half (64 cols)
    const int sx = fr & 7;           // read-side swizzle mask

    // staging: wave w covers rows w*32..w*32+31 of the 128-row tile (4 gloads
    // of 8 rows each, for A and for B). lane l -> row_local = l>>3; fetch
    // global k-slot (l&7)^(l>>3) so the linear LDS write lands pre-swizzled
    // (both-sides involution, rule #21).
    const int lrow = lane >> 3;
    const int lslot = (lane & 7) ^ lrow;
    const bf16* gA = A + (size_t)(bm * 128 + w * 32 + lrow) * K + lslot * 8;
    const bf16* gB = Bt + (size_t)(bn * 128 + w * 32 + lrow) * K + lslot * 8;

    f32x4 acc[4][4];
#pragma unroll
    for (int i = 0; i < 4; ++i)
#pragma unroll
        for (int j = 0; j < 4; ++j) acc[i][j] = {0.f, 0.f, 0.f, 0.f};

#define STAGE(T, BUF)                                                          \
    do {                                                                       \
        _Pragma("unroll") for (int r = 0; r < 4; ++r)                          \
            gload_lds16(gA + (size_t)(T) * 64 + (size_t)(r * 8) * K,           \
                        &ldsA[BUF][0] + w * 2048 + r * 512);                   \
        _Pragma("unroll") for (int r = 0; r < 4; ++r)                          \
            gload_lds16(gB + (size_t)(T) * 64 + (size_t)(r * 8) * K,           \
                        &ldsB[BUF][0] + w * 2048 + r * 512);                   \
    } while (0)

    // prologue: tiles 0,1 staged (16 gloads); wait tile 0's 8 (tile 1 in flight)
    STAGE(0, 0);
    STAGE(1, 1);
    WAITV(8);
    SBAR();

    for (int t = 0; t < NT; ++t) {
        const int c = t & 1;
#pragma unroll
        for (int ks = 0; ks < 2; ++ks) {
            bf16x8 bq[4], af[4];
#pragma unroll
            for (int nt = 0; nt < 4; ++nt) {
                int row = wn * 64 + nt * 16 + fr;
                int sl = ((ks << 2) | fq) ^ sx;
                bq[nt] = *(const bf16x8*)((const char*)&ldsB[c][0] +
                                          row * 128 + sl * 16);
            }
#pragma unroll
            for (int mt = 0; mt < 4; ++mt) {
                int row = wm * 64 + mt * 16 + fr;
                int sl = ((ks << 2) | fq) ^ sx;
                af[mt] = *(const bf16x8*)((const char*)&ldsA[c][0] +
                                          row * 128 + sl * 16);
            }
            __builtin_amdgcn_s_setprio(1);
#pragma unroll
            for (int mt = 0; mt < 4; ++mt)
#pragma unroll
                for (int nt = 0; nt < 4; ++nt)
                    acc[mt][nt] = __builtin_amdgcn_mfma_f32_16x16x32_bf16(
                        af[mt], bq[nt], acc[mt][nt], 0, 0, 0);
            __builtin_amdgcn_s_setprio(0);
        }
        // boundary: own reads of buf c drained (WAR), tile t+1's gloads landed
        // (RAW; cold — issued a full tile ago), barrier, restage c with t+2.
        if (t + 1 < NT) {
            WAITL0();
            WAITV(0);
            SBAR();
            if (t + 2 < NT) STAGE(t + 2, c);
        }
    }
#undef STAGE

    // epilogue: scalar store (C/D layout verified m89/m91: col = lane&15,
    // row = (lane>>4)*4 + reg). WRITE_SIZE measured ~ideal with this pattern.
    float bv[4];
    if (RELU_BIAS) {
#pragma unroll
        for (int nt = 0; nt < 4; ++nt) {
            int col = bn * 128 + wn * 64 + nt * 16 + fr;
            bv[nt] = (col < DMID) ? bias[col] : 0.0f;
        }
    }
#pragma unroll
    for (int mq = 0; mq < 4; ++mq) {
        int row0 = bm * 128 + wm * 64 + mq * 16 + fq * 4;
#pragma unroll
        for (int nt = 0; nt < 4; ++nt) {
            int col = bn * 128 + wn * 64 + nt * 16 + fr;
#pragma unroll
            for (int r = 0; r < 4; ++r) {
                float v = acc[mq][nt][r];
                if (RELU_BIAS) v = fmaxf(v + bv[nt], 0.0f);
                C[(size_t)(row0 + r) * N + col] = (bf16)v;
            }
        }
    }
}

// ---------------- aggregation (CSR gather, barrier-free) ----------------
// R4 version (8 gathers in flight); R6's 16-batch cost +12 us (VGPR pressure).

// XA[i] = isd_i^2 * X[i] + sum_j w_ij * X[j], 1024-wide bf16 in/out
__global__ __launch_bounds__(128) void k_aggX(const bf16* __restrict__ X,
                                              const int* __restrict__ rowptr,
                                              const int* __restrict__ csr_src,
                                              const float* __restrict__ csr_w,
                                              const float* __restrict__ isd,
                                              bf16* __restrict__ XA) {
    int i = blockIdx.x;
    int t = threadIdx.x;      // 128 threads * 8 cols = 1024
    int c0 = t * 8;
    int beg = rowptr[i], end = rowptr[i + 1];  // uniform; (end-beg) % 8 == 0
    float wi = isd[i];
    float w0 = wi * wi;
    float a[8];
    bf16x8 h = *(const bf16x8*)&X[(size_t)i * DIN + c0];
#pragma unroll
    for (int k = 0; k < 8; ++k) a[k] = w0 * (float)h[k];
    for (int e = beg; e < end; e += 8) {
        int j[8];
        float w[8];
        bf16x8 hv[8];
#pragma unroll
        for (int q = 0; q < 8; ++q) { j[q] = csr_src[e + q]; w[q] = csr_w[e + q]; }
#pragma unroll
        for (int q = 0; q < 8; ++q)
            hv[q] = *(const bf16x8*)&X[(size_t)j[q] * DIN + c0];
#pragma unroll
        for (int q = 0; q < 8; ++q)
#pragma unroll
            for (int k = 0; k < 8; ++k) a[k] += w[q] * (float)hv[q][k];
    }
    bf16x8 o;
#pragma unroll
    for (int k = 0; k < 8; ++k) o[k] = (bf16)a[k];
    *(bf16x8*)&XA[(size_t)i * DIN + c0] = o;
}

// layer 2: out[i] = isd_i^2 * H[i] + sum_j w_ij * H[j] + b2, f32 out
__global__ __launch_bounds__(128) void k_agg2(const bf16* __restrict__ H,
                                              const int* __restrict__ rowptr,
                                              const int* __restrict__ csr_src,
                                              const float* __restrict__ csr_w,
                                              const float* __restrict__ isd,
                                              const float* __restrict__ b2,
                                              float* __restrict__ out) {
    int i = blockIdx.x;
    int t = threadIdx.x;      // 128 threads * 8 cols = 1024
    int c0 = t * 8;
    int beg = rowptr[i], end = rowptr[i + 1];
    float wi = isd[i];
    float w0 = wi * wi;
    float a[8];
    bf16x8 h = *(const bf16x8*)&H[(size_t)i * DIN + c0];
#pragma unroll
    for (int k = 0; k < 8; ++k) a[k] = w0 * (float)h[k];
    for (int e = beg; e < end; e += 8) {
        int j[8];
        float w[8];
        bf16x8 hv[8];
#pragma unroll
        for (int q = 0; q < 8; ++q) { j[q] = csr_src[e + q]; w[q] = csr_w[e + q]; }
#pragma unroll
        for (int q = 0; q < 8; ++q)
            hv[q] = *(const bf16x8*)&H[(size_t)j[q] * DIN + c0];
#pragma unroll
        for (int q = 0; q < 8; ++q)
#pragma unroll
            for (int k = 0; k < 8; ++k) a[k] += w[q] * (float)hv[q][k];
    }
    float4 o0, o1;
    o0.x = a[0] + b2[c0 + 0]; o0.y = a[1] + b2[c0 + 1];
    o0.z = a[2] + b2[c0 + 2]; o0.w = a[3] + b2[c0 + 3];
    o1.x = a[4] + b2[c0 + 4]; o1.y = a[5] + b2[c0 + 5];
    o1.z = a[6] + b2[c0 + 6]; o1.w = a[7] + b2[c0 + 7];
    *(float4*)&out[(size_t)i * DIN + c0] = o0;
    *(float4*)&out[(size_t)i * DIN + c0 + 4] = o1;
}

extern "C" void kernel_launch(void* const* d_in, const int* in_sizes, int n_in,
                              void* d_out, int out_size, void* d_ws, size_t ws_size,
                              hipStream_t stream) {
    const float* x = (const float*)d_in[0];
    const int* ei = (const int*)d_in[1];
    const float* W1 = (const float*)d_in[2];
    const float* b1 = (const float*)d_in[3];
    const float* W2 = (const float*)d_in[4];
    const float* b2 = (const float*)d_in[5];
    float* out = (float*)d_out;
    const int* src = ei;
    const int* dst = ei + NE;

    // workspace layout (bytes), total ~122 MB
    char* ws = (char*)d_ws;
    int* cnt      = (int*)(ws + 0);          //  64 KB
    int* cursor   = (int*)(ws + 65536);      //  64 KB
    float* isd    = (float*)(ws + 131072);   //  64 KB
    int* rowptr   = (int*)(ws + 196608);     // 128 KB (NN+1 ints)
    int* csr_src  = (int*)(ws + 327680);     //   2 MB (padded <= 245760 entries)
    float* csr_w  = (float*)(ws + 2424832);  //   2 MB
    bf16* Xb      = (bf16*)(ws + 4521984);   // 33.55 MB (16384x1024)
    bf16* XA      = (bf16*)(ws + 38076416);  // 33.55 MB — reused as H2b
    bf16* W1b     = (bf16*)(ws + 71630848);  //  3.15 MB (1536x1024, transposed)
    bf16* W2b     = (bf16*)(ws + 74776576);  //  3.15 MB (1024x1536, transposed)
    bf16* Y1b     = (bf16*)(ws + 77922304);  // 50.33 MB (16384x1536)
    bf16* H2b     = XA;                      // XA dead after GEMM1

    // CSR + normalization
    k_zero_cnt<<<NN / 256, 256, 0, stream>>>(cnt);
    k_count<<<NE / 256, 256, 0, stream>>>(dst, cnt);
    k_scan<<<1, 1024, 0, stream>>>(cnt, rowptr, cursor, isd);
    k_fill<<<NE / 256, 256, 0, stream>>>(src, dst, cursor, isd, csr_src, csr_w);
    k_pad<<<NN / 256, 256, 0, stream>>>(cnt, rowptr, csr_src, csr_w);

    // bf16 conversions
    k_cvt_x<<<NN * DIN / 4 / 256, 256, 0, stream>>>((const float4*)x, (bf16x4*)Xb);
    {
        dim3 gw1(DMIDP / 32, DIN / 32);
        k_cvt_w1<<<gw1, 256, 0, stream>>>(W1, W1b);
        dim3 gw2(DIN / 32, DMIDP / 32);
        k_cvt_w2<<<gw2, 256, 0, stream>>>(W2, W2b);
    }

    // layer 1: XA = A_hat @ X ; Y1 = relu(XA @ W1 + b1)   [agg commutes with linear]
    k_aggX<<<NN, 128, 0, stream>>>(Xb, rowptr, csr_src, csr_w, isd, XA);
    dim3 g1(NN / 128, DMIDP / 128);   // 1536 blocks -> 3 tailless rounds @2/CU
    gemm128<DIN, DMIDP, true><<<g1, 256, 0, stream>>>(XA, W1b, Y1b, b1);

    // layer 2: H2 = Y1 @ W2 ; out = A_hat @ H2 + b2
    dim3 g2(NN / 128, DIN / 128);     // 1024 blocks -> 2 rounds @2/CU
    gemm128<DMIDP, DIN, false><<<g2, 256, 0, stream>>>(Y1b, W2b, H2b, nullptr);
    k_agg2<<<NN, 128, 0, stream>>>(H2b, rowptr, csr_src, csr_w, isd, b2, out);
}

// Round 8
// 366.118 us; speedup vs baseline: 1.3916x; 1.0129x over previous
//
#include <hip/hip_runtime.h>
#include <cstdint>
#include <cstddef>

// Problem constants (fixed by the reference)
#define NN 16384      // nodes
#define DIN 1024      // hid_size
#define DMID 1500     // hidden_size (logical)
#define DMIDP 1536    // padded to multiple of 128
#define NE 131072     // edges

typedef __bf16 bf16;
typedef __bf16 bf16x4 __attribute__((ext_vector_type(4)));
typedef __bf16 bf16x8 __attribute__((ext_vector_type(8)));
typedef float f32x4 __attribute__((ext_vector_type(4)));

#define GLOBAL_AS __attribute__((address_space(1)))
#define LDS_AS __attribute__((address_space(3)))

__device__ __forceinline__ void gload_lds16(const bf16* g, bf16* l) {
    // async 16B/lane global->LDS; LDS dest is wave-uniform base + lane*16
    __builtin_amdgcn_global_load_lds((GLOBAL_AS const unsigned int*)(g),
                                     (LDS_AS unsigned int*)(l), 16, 0, 0);
}

// ---------------- CSR build + normalization ----------------
__global__ void k_zero_cnt(int* cnt) {
    cnt[blockIdx.x * 256 + threadIdx.x] = 0;
}

__global__ void k_count(const int* __restrict__ dst, int* cnt) {
    int e = blockIdx.x * 256 + threadIdx.x;
    atomicAdd(&cnt[dst[e]], 1);
}

// single block, 1024 threads, 16 nodes each.
// rowptr = exclusive scan of PADDED counts (pad to multiple of 8); cursor = start; isd.
__global__ __launch_bounds__(1024) void k_scan(const int* __restrict__ cnt,
                                               int* __restrict__ rowptr,
                                               int* __restrict__ cursor,
                                               float* __restrict__ isd) {
    __shared__ int sums[1024];
    int t = threadIdx.x;
    int base = t * 16;
    int v[16], p[16];
    int s = 0;
#pragma unroll
    for (int k = 0; k < 16; ++k) {
        v[k] = cnt[base + k];
        p[k] = (v[k] + 7) & ~7;  // padded row length (multiple of 8)
        s += p[k];
    }
    sums[t] = s;
    __syncthreads();
    for (int off = 1; off < 1024; off <<= 1) {
        int y = (t >= off) ? sums[t - off] : 0;
        __syncthreads();
        sums[t] += y;
        __syncthreads();
    }
    int run = sums[t] - s;  // exclusive prefix
#pragma unroll
    for (int k = 0; k < 16; ++k) {
        rowptr[base + k] = run;
        cursor[base + k] = run;
        isd[base + k] = rsqrtf((float)(v[k] + 1));  // +1 self-loop
        run += p[k];
    }
    if (t == 1023) rowptr[NN] = run;
}

__global__ void k_fill(const int* __restrict__ src, const int* __restrict__ dst,
                       int* cursor, const float* __restrict__ isd,
                       int* __restrict__ csr_src, float* __restrict__ csr_w) {
    int e = blockIdx.x * 256 + threadIdx.x;
    int s = src[e], d = dst[e];
    int pos = atomicAdd(&cursor[d], 1);
    csr_src[pos] = s;
    csr_w[pos] = isd[s] * isd[d];
}

// fill pad slots: src = self (L1-hot row), w = 0 (contributes nothing)
__global__ void k_pad(const int* __restrict__ cnt, const int* __restrict__ rowptr,
                      int* __restrict__ csr_src, float* __restrict__ csr_w) {
    int i = blockIdx.x * 256 + threadIdx.x;
    int c = cnt[i];
    int p = (c + 7) & ~7;
    int base = rowptr[i];
    for (int q = c; q < p; ++q) {
        csr_src[base + q] = i;
        csr_w[base + q] = 0.0f;
    }
}

// ---------------- conversions ----------------
__global__ void k_cvt_x(const float4* __restrict__ x, bf16x4* __restrict__ xb) {
    int i = blockIdx.x * 256 + threadIdx.x;  // NN*DIN/4 total
    float4 v = x[i];
    bf16x4 o;
    o[0] = (bf16)v.x; o[1] = (bf16)v.y; o[2] = (bf16)v.z; o[3] = (bf16)v.w;
    xb[i] = o;
}

// LDS-tile transposes for the weight conversions (R7; both global sides coalesced).

// W1 [1024][1500] f32 -> W1b [1536][1024] bf16 (W1b[n][k] = W1[k][n], n-pad 0)
// grid (DMIDP/32 = 48, DIN/32 = 32), 256 threads
__global__ __launch_bounds__(256) void k_cvt_w1(const float* __restrict__ W1,
                                                bf16* __restrict__ W1b) {
    __shared__ float t[32][33];
    int n0 = blockIdx.x * 32;   // 0..1535 (output row = W1 col)
    int k0 = blockIdx.y * 32;   // 0..1023
    int tx = threadIdx.x & 31, ty = threadIdx.x >> 5;  // ty 0..7
#pragma unroll
    for (int p = 0; p < 4; ++p) {
        int n = n0 + tx;
        t[p * 8 + ty][tx] = (n < DMID)
            ? W1[(size_t)(k0 + p * 8 + ty) * DMID + n] : 0.0f;
    }
    __syncthreads();
#pragma unroll
    for (int p = 0; p < 4; ++p) {
        int n = n0 + p * 8 + ty;
        W1b[(size_t)n * DIN + k0 + tx] = (bf16)t[tx][p * 8 + ty];
    }
}

// W2 [1500][1024] f32 -> W2b [1024][1536] bf16 (W2b[n][k] = W2[k][n], k-pad 0)
// grid (DIN/32 = 32, DMIDP/32 = 48), 256 threads
__global__ __launch_bounds__(256) void k_cvt_w2(const float* __restrict__ W2,
                                                bf16* __restrict__ W2b) {
    __shared__ float t[32][33];
    int n0 = blockIdx.x * 32;   // 0..1023 (output row = W2 col)
    int k0 = blockIdx.y * 32;   // 0..1535
    int tx = threadIdx.x & 31, ty = threadIdx.x >> 5;
#pragma unroll
    for (int p = 0; p < 4; ++p) {
        int k = k0 + p * 8 + ty;
        t[p * 8 + ty][tx] = (k < DMID)
            ? W2[(size_t)k * DIN + n0 + tx] : 0.0f;
    }
    __syncthreads();
#pragma unroll
    for (int p = 0; p < 4; ++p) {
        int n = n0 + p * 8 + ty;
        W2b[(size_t)n * DMIDP + k0 + tx] = (bf16)t[tx][p * 8 + ty];
    }
}

// ---------------- GEMM: C[M,N] = A[M,K] @ Bt[N,K]^T, bf16 in / bf16 out ----------------
// R8: m97-anchor config — 128x128 tile, BK=64, SINGLE-buffered 32 KB LDS ->
// 5 blocks/CU (LDS-capped), 20 waves/CU. R7 confirmed the occupancy gradient:
// 1 blk/CU = 667 TF (R1-R6, schedule-invariant), 2 blk/CU = 803 TF (R7).
// Single-buffer costs a vmcnt(0) drain per tile (compiler emits it before
// s_barrier) but buys 2.5x more co-resident blocks to fill that drain —
// the measured m97 trade (874-912 TF with MORE conflicts than we have).
// Keeps: T2 pre-swizzle (0 conflicts since R1), width-16 gload_lds, setprio.
// 4 waves (2Mx2N), per-wave 64x64 output.
template <int K, int N, bool RELU_BIAS>
__global__ __launch_bounds__(256, 4) void gemm128(const bf16* __restrict__ A,
                                                  const bf16* __restrict__ Bt,
                                                  bf16* __restrict__ C,
                                                  const float* __restrict__ bias) {
    constexpr int NT = K / 64;
    __shared__ __align__(16) bf16 ldsA[128 * 64];  // 16 KB
    __shared__ __align__(16) bf16 ldsB[128 * 64];  // 16 KB -> 32 KB total
    const int tid = threadIdx.x;
    const int w = tid >> 6;          // 0..3
    const int lane = tid & 63;
    const int bm = blockIdx.x, bn = blockIdx.y;
    const int fr = lane & 15, fq = lane >> 4;
    const int wm = w & 1;            // M half (64 rows)
    const int wn = w >> 1;           // N half (64 cols)
    const int sx = fr & 7;           // read-side swizzle mask

    // staging: wave w covers rows w*32..w*32+31 (4 gloads of 8 rows, A and B).
    // lane l -> row_local = l>>3; fetch global k-slot (l&7)^(l>>3) so the
    // linear LDS write lands pre-swizzled (both-sides involution, rule #21).
    const int lrow = lane >> 3;
    const int lslot = (lane & 7) ^ lrow;
    const bf16* gA = A + (size_t)(bm * 128 + w * 32 + lrow) * K + lslot * 8;
    const bf16* gB = Bt + (size_t)(bn * 128 + w * 32 + lrow) * K + lslot * 8;

    f32x4 acc[4][4];
#pragma unroll
    for (int i = 0; i < 4; ++i)
#pragma unroll
        for (int j = 0; j < 4; ++j) acc[i][j] = {0.f, 0.f, 0.f, 0.f};

    for (int t = 0; t < NT; ++t) {
#pragma unroll
        for (int r = 0; r < 4; ++r)
            gload_lds16(gA + (size_t)t * 64 + (size_t)(r * 8) * K,
                        &ldsA[0] + w * 2048 + r * 512);
#pragma unroll
        for (int r = 0; r < 4; ++r)
            gload_lds16(gB + (size_t)t * 64 + (size_t)(r * 8) * K,
                        &ldsB[0] + w * 2048 + r * 512);
        __syncthreads();  // compiler emits vmcnt(0) lgkm(0) before s_barrier (RAW)
#pragma unroll
        for (int ks = 0; ks < 2; ++ks) {
            bf16x8 bq[4], af[4];
#pragma unroll
            for (int nt = 0; nt < 4; ++nt) {
                int row = wn * 64 + nt * 16 + fr;
                int sl = ((ks << 2) | fq) ^ sx;
                bq[nt] = *(const bf16x8*)((const char*)&ldsB[0] +
                                          row * 128 + sl * 16);
            }
#pragma unroll
            for (int mt = 0; mt < 4; ++mt) {
                int row = wm * 64 + mt * 16 + fr;
                int sl = ((ks << 2) | fq) ^ sx;
                af[mt] = *(const bf16x8*)((const char*)&ldsA[0] +
                                          row * 128 + sl * 16);
            }
            __builtin_amdgcn_s_setprio(1);
#pragma unroll
            for (int mt = 0; mt < 4; ++mt)
#pragma unroll
                for (int nt = 0; nt < 4; ++nt)
                    acc[mt][nt] = __builtin_amdgcn_mfma_f32_16x16x32_bf16(
                        af[mt], bq[nt], acc[mt][nt], 0, 0, 0);
            __builtin_amdgcn_s_setprio(0);
        }
        __syncthreads();  // WAR: all reads drained before next tile's staging
    }

    // epilogue: scalar store (C/D layout verified m89/m91: col = lane&15,
    // row = (lane>>4)*4 + reg). WRITE_SIZE measured ~ideal with this pattern.
    float bv[4];
    if (RELU_BIAS) {
#pragma unroll
        for (int nt = 0; nt < 4; ++nt) {
            int col = bn * 128 + wn * 64 + nt * 16 + fr;
            bv[nt] = (col < DMID) ? bias[col] : 0.0f;
        }
    }
#pragma unroll
    for (int mq = 0; mq < 4; ++mq) {
        int row0 = bm * 128 + wm * 64 + mq * 16 + fq * 4;
#pragma unroll
        for (int nt = 0; nt < 4; ++nt) {
            int col = bn * 128 + wn * 64 + nt * 16 + fr;
#pragma unroll
            for (int r = 0; r < 4; ++r) {
                float v = acc[mq][nt][r];
                if (RELU_BIAS) v = fmaxf(v + bv[nt], 0.0f);
                C[(size_t)(row0 + r) * N + col] = (bf16)v;
            }
        }
    }
}

// ---------------- aggregation (CSR gather, barrier-free) ----------------
// R4 version (8 gathers in flight); R6's 16-batch cost +12 us (VGPR pressure).

// XA[i] = isd_i^2 * X[i] + sum_j w_ij * X[j], 1024-wide bf16 in/out
__global__ __launch_bounds__(128) void k_aggX(const bf16* __restrict__ X,
                                              const int* __restrict__ rowptr,
                                              const int* __restrict__ csr_src,
                                              const float* __restrict__ csr_w,
                                              const float* __restrict__ isd,
                                              bf16* __restrict__ XA) {
    int i = blockIdx.x;
    int t = threadIdx.x;      // 128 threads * 8 cols = 1024
    int c0 = t * 8;
    int beg = rowptr[i], end = rowptr[i + 1];  // uniform; (end-beg) % 8 == 0
    float wi = isd[i];
    float w0 = wi * wi;
    float a[8];
    bf16x8 h = *(const bf16x8*)&X[(size_t)i * DIN + c0];
#pragma unroll
    for (int k = 0; k < 8; ++k) a[k] = w0 * (float)h[k];
    for (int e = beg; e < end; e += 8) {
        int j[8];
        float w[8];
        bf16x8 hv[8];
#pragma unroll
        for (int q = 0; q < 8; ++q) { j[q] = csr_src[e + q]; w[q] = csr_w[e + q]; }
#pragma unroll
        for (int q = 0; q < 8; ++q)
            hv[q] = *(const bf16x8*)&X[(size_t)j[q] * DIN + c0];
#pragma unroll
        for (int q = 0; q < 8; ++q)
#pragma unroll
            for (int k = 0; k < 8; ++k) a[k] += w[q] * (float)hv[q][k];
    }
    bf16x8 o;
#pragma unroll
    for (int k = 0; k < 8; ++k) o[k] = (bf16)a[k];
    *(bf16x8*)&XA[(size_t)i * DIN + c0] = o;
}

// layer 2: out[i] = isd_i^2 * H[i] + sum_j w_ij * H[j] + b2, f32 out
__global__ __launch_bounds__(128) void k_agg2(const bf16* __restrict__ H,
                                              const int* __restrict__ rowptr,
                                              const int* __restrict__ csr_src,
                                              const float* __restrict__ csr_w,
                                              const float* __restrict__ isd,
                                              const float* __restrict__ b2,
                                              float* __restrict__ out) {
    int i = blockIdx.x;
    int t = threadIdx.x;      // 128 threads * 8 cols = 1024
    int c0 = t * 8;
    int beg = rowptr[i], end = rowptr[i + 1];
    float wi = isd[i];
    float w0 = wi * wi;
    float a[8];
    bf16x8 h = *(const bf16x8*)&H[(size_t)i * DIN + c0];
#pragma unroll
    for (int k = 0; k < 8; ++k) a[k] = w0 * (float)h[k];
    for (int e = beg; e < end; e += 8) {
        int j[8];
        float w[8];
        bf16x8 hv[8];
#pragma unroll
        for (int q = 0; q < 8; ++q) { j[q] = csr_src[e + q]; w[q] = csr_w[e + q]; }
#pragma unroll
        for (int q = 0; q < 8; ++q)
            hv[q] = *(const bf16x8*)&H[(size_t)j[q] * DIN + c0];
#pragma unroll
        for (int q = 0; q < 8; ++q)
#pragma unroll
            for (int k = 0; k < 8; ++k) a[k] += w[q] * (float)hv[q][k];
    }
    float4 o0, o1;
    o0.x = a[0] + b2[c0 + 0]; o0.y = a[1] + b2[c0 + 1];
    o0.z = a[2] + b2[c0 + 2]; o0.w = a[3] + b2[c0 + 3];
    o1.x = a[4] + b2[c0 + 4]; o1.y = a[5] + b2[c0 + 5];
    o1.z = a[6] + b2[c0 + 6]; o1.w = a[7] + b2[c0 + 7];
    *(float4*)&out[(size_t)i * DIN + c0] = o0;
    *(float4*)&out[(size_t)i * DIN + c0 + 4] = o1;
}

extern "C" void kernel_launch(void* const* d_in, const int* in_sizes, int n_in,
                              void* d_out, int out_size, void* d_ws, size_t ws_size,
                              hipStream_t stream) {
    const float* x = (const float*)d_in[0];
    const int* ei = (const int*)d_in[1];
    const float* W1 = (const float*)d_in[2];
    const float* b1 = (const float*)d_in[3];
    const float* W2 = (const float*)d_in[4];
    const float* b2 = (const float*)d_in[5];
    float* out = (float*)d_out;
    const int* src = ei;
    const int* dst = ei + NE;

    // workspace layout (bytes), total ~122 MB
    char* ws = (char*)d_ws;
    int* cnt      = (int*)(ws + 0);          //  64 KB
    int* cursor   = (int*)(ws + 65536);      //  64 KB
    float* isd    = (float*)(ws + 131072);   //  64 KB
    int* rowptr   = (int*)(ws + 196608);     // 128 KB (NN+1 ints)
    int* csr_src  = (int*)(ws + 327680);     //   2 MB (padded <= 245760 entries)
    float* csr_w  = (float*)(ws + 2424832);  //   2 MB
    bf16* Xb      = (bf16*)(ws + 4521984);   // 33.55 MB (16384x1024)
    bf16* XA      = (bf16*)(ws + 38076416);  // 33.55 MB — reused as H2b
    bf16* W1b     = (bf16*)(ws + 71630848);  //  3.15 MB (1536x1024, transposed)
    bf16* W2b     = (bf16*)(ws + 74776576);  //  3.15 MB (1024x1536, transposed)
    bf16* Y1b     = (bf16*)(ws + 77922304);  // 50.33 MB (16384x1536)
    bf16* H2b     = XA;                      // XA dead after GEMM1

    // CSR + normalization
    k_zero_cnt<<<NN / 256, 256, 0, stream>>>(cnt);
    k_count<<<NE / 256, 256, 0, stream>>>(dst, cnt);
    k_scan<<<1, 1024, 0, stream>>>(cnt, rowptr, cursor, isd);
    k_fill<<<NE / 256, 256, 0, stream>>>(src, dst, cursor, isd, csr_src, csr_w);
    k_pad<<<NN / 256, 256, 0, stream>>>(cnt, rowptr, csr_src, csr_w);

    // bf16 conversions
    k_cvt_x<<<NN * DIN / 4 / 256, 256, 0, stream>>>((const float4*)x, (bf16x4*)Xb);
    {
        dim3 gw1(DMIDP / 32, DIN / 32);
        k_cvt_w1<<<gw1, 256, 0, stream>>>(W1, W1b);
        dim3 gw2(DIN / 32, DMIDP / 32);
        k_cvt_w2<<<gw2, 256, 0, stream>>>(W2, W2b);
    }

    // layer 1: XA = A_hat @ X ; Y1 = relu(XA @ W1 + b1)   [agg commutes with linear]
    k_aggX<<<NN, 128, 0, stream>>>(Xb, rowptr, csr_src, csr_w, isd, XA);
    dim3 g1(NN / 128, DMIDP / 128);   // 1536 blocks @5/CU -> 1.2 rounds (streamed)
    gemm128<DIN, DMIDP, true><<<g1, 256, 0, stream>>>(XA, W1b, Y1b, b1);

    // layer 2: H2 = Y1 @ W2 ; out = A_hat @ H2 + b2
    dim3 g2(NN / 128, DIN / 128);     // 1024 blocks @5/CU -> 0.8 round
    gemm128<DMIDP, DIN, false><<<g2, 256, 0, stream>>>(Y1b, W2b, H2b, nullptr);
    k_agg2<<<NN, 128, 0, stream>>>(H2b, rowptr, csr_src, csr_w, isd, b2, out);
}